// Round 6
// baseline (150.370 us; speedup 1.0000x reference)
//
#include <hip/hip_runtime.h>
#include <hip/hip_bf16.h>

// ---------------------------------------------------------------------------
// EmbeddingGATHead: pool -> GATv2 (2 layers, 4 heads, block-diag mask) ->
// residual -> part-mean -> BN.
// Round 6: R5 design (single-pass GEMM, no split-K/P/LDS/barriers, depth-4
// register ring, fused bias) with the W head-stride addressing bug fixed:
// W is [4][2048][512]; col bcol -> head = bcol>>9, d = bcol&511.
// Node order: n = p*32 + b.  Instance g = n // 6, valid iff (n % 6) < nps[g].
// ---------------------------------------------------------------------------

#define NNODES 192
#define CFEAT  2048

typedef __attribute__((ext_vector_type(8))) short bf16x8;   // 8 bf16 = 4 VGPR
typedef __attribute__((ext_vector_type(4))) float f32x4;

__device__ inline unsigned f2bf(float f) {                 // RNE f32 -> bf16
    union { float f; unsigned u; } v; v.f = f;
    unsigned u = v.u;
    u += 0x7FFFu + ((u >> 16) & 1u);
    return u >> 16;
}

// ---- 1. Global average pool: features [32][12288][16][8] -> pool [192][2048]
__global__ __launch_bounds__(256) void pool_kernel(const float* __restrict__ F,
                                                   float* __restrict__ POOL,
                                                   unsigned short* __restrict__ POOLB) {
    int wave = threadIdx.x >> 6, lane = threadIdx.x & 63;
    #pragma unroll
    for (int it = 0; it < 12; ++it) {
        int dr = blockIdx.x * 4 + wave + it * 16384;   // [0, 196608)
        int r0 = dr * 2;                               // (n,c) pair index
        int n = r0 >> 11, c0 = r0 & 2047;
        int p = n >> 5, b = n & 31;                    // n = p*32 + b
        const float* src = F + (((size_t)b * 12288 + (size_t)p * 2048 + c0) << 7);
        float4 v = *(const float4*)(src + (lane << 2));
        float acc = (v.x + v.y) + (v.z + v.w);
        acc += __shfl_down(acc, 16);
        acc += __shfl_down(acc, 8);
        acc += __shfl_down(acc, 4);
        acc += __shfl_down(acc, 2);
        acc += __shfl_down(acc, 1);
        if ((lane & 31) == 0) {                        // lanes 0 and 32
            int r = r0 + (lane >> 5);
            float m = acc * (1.0f / 128.0f);
            POOL[r] = m;
            POOLB[r] = (unsigned short)f2bf(m);
        }
    }
}

// ---- 2. Single-pass GEMM: Y[192][4096] = X[192][2048] @ [Wl|Wr] + bias.
// grid = 128 blocks: block ct -> 32 cols (ct<64: Wl flat-cols ct*32.. ; else Wr).
// 4 waves: wave w = rows 48w..48w+47 (3 frags) x 32 cols (2 frags) = 6 MFMA/step.
// No LDS, no barriers: A-frags 16B direct loads (L2-hot); B = 16 strided dwords
// per step (full 128B line per k-row per wave), depth-4 register ring.
__global__ __launch_bounds__(256) void gemm_kernel(
    const unsigned short* __restrict__ X,    // bf16 [192][2048]
    const float* __restrict__ WL,            // fp32 [4][2048][512] (layer slice)
    const float* __restrict__ WR,
    const float* __restrict__ BL,            // fp32 [4][512] (flat 2048)
    const float* __restrict__ BR,
    float* __restrict__ Y) {                 // fp32 [192][4096]
    int ct = blockIdx.x;
    int t = threadIdx.x, w = t >> 6, l = t & 63;
    int lr = l & 15, lg = l >> 4;

    int bcol = ((ct & 63) << 5) + lr;        // flat col = head*512 + d
    int head = bcol >> 9, dcol = bcol & 511; // W is head-major [4][2048][512]
    const float* Wb = ((ct >= 64) ? WR : WL)
                    + (size_t)head * (2048 * 512) + dcol;      // + k*512 (+16 for cf=1)
    const unsigned short* Xp = X + (size_t)(48 * w + lr) * 2048 + lg * 8;

    f32x4 acc[3][2];
    #pragma unroll
    for (int i = 0; i < 3; ++i)
        #pragma unroll
        for (int j = 0; j < 2; ++j) acc[i][j] = {0.f, 0.f, 0.f, 0.f};

    float  fb[4][16];    // B ring: [slot][cf*8 + j]
    bf16x8 fa[4][3];     // A ring: [slot][fi]

    // issue loads for step into ring slot (indices constant after unroll)
#define LOAD_SLOT(slot, step)                                                 \
    {                                                                         \
        const float* wp = Wb + (size_t)(((step) << 5) + lg * 8) * 512;        \
        _Pragma("unroll")                                                     \
        for (int j = 0; j < 8; ++j) {                                         \
            fb[slot][j]     = wp[(size_t)j * 512];                            \
            fb[slot][8 + j] = wp[(size_t)j * 512 + 16];                       \
        }                                                                     \
        const unsigned short* xp = Xp + ((step) << 5);                        \
        fa[slot][0] = *(const bf16x8*)(xp);                                   \
        fa[slot][1] = *(const bf16x8*)(xp + 16 * 2048);                       \
        fa[slot][2] = *(const bf16x8*)(xp + 32 * 2048);                       \
    }

    #pragma unroll
    for (int s = 0; s < 4; ++s) LOAD_SLOT(s, s)

    for (int it = 0; it < 64; it += 4) {
        #pragma unroll
        for (int u = 0; u < 4; ++u) {
            int s = it + u;
            // consume slot u: convert B to bf16 frags, run 6 MFMA
            bf16x8 bf0, bf1;
            #pragma unroll
            for (int j = 0; j < 8; ++j) {
                bf0[j] = (short)__builtin_bit_cast(unsigned short,
                              __float2bfloat16(fb[u][j]));
                bf1[j] = (short)__builtin_bit_cast(unsigned short,
                              __float2bfloat16(fb[u][8 + j]));
            }
            acc[0][0] = __builtin_amdgcn_mfma_f32_16x16x32_bf16(fa[u][0], bf0, acc[0][0], 0, 0, 0);
            acc[0][1] = __builtin_amdgcn_mfma_f32_16x16x32_bf16(fa[u][0], bf1, acc[0][1], 0, 0, 0);
            acc[1][0] = __builtin_amdgcn_mfma_f32_16x16x32_bf16(fa[u][1], bf0, acc[1][0], 0, 0, 0);
            acc[1][1] = __builtin_amdgcn_mfma_f32_16x16x32_bf16(fa[u][1], bf1, acc[1][1], 0, 0, 0);
            acc[2][0] = __builtin_amdgcn_mfma_f32_16x16x32_bf16(fa[u][2], bf0, acc[2][0], 0, 0, 0);
            acc[2][1] = __builtin_amdgcn_mfma_f32_16x16x32_bf16(fa[u][2], bf1, acc[2][1], 0, 0, 0);
            // issue step s+4 into the slot just consumed
            if (s + 4 < 64) LOAD_SLOT(u, s + 4)
        }
    }
#undef LOAD_SLOT

    // epilogue: D row = (lane>>4)*4 + reg (frag fi at base 16*fi), col = lane&15
    float b0 = ((ct >= 64) ? BR : BL)[bcol];
    float b1 = ((ct >= 64) ? BR : BL)[bcol + 16];
    int ycol = ((ct >= 64) ? 2048 : 0) + bcol;
    #pragma unroll
    for (int fi = 0; fi < 3; ++fi) {
        int rbase = 48 * w + 16 * fi + lg * 4;
        #pragma unroll
        for (int j = 0; j < 4; ++j) {
            float* dst = Y + (size_t)(rbase + j) * 4096 + ycol;
            dst[0]  = acc[fi][0][j] + b0;
            dst[16] = acc[fi][1][j] + b1;
        }
    }
}

// ---- 3. Attention per (instance g, head h). Y: [192][4096], xl cols 0..2047,
// xr cols 2048..4095 (bias already included).
template <int LAYER>
__global__ __launch_bounds__(256) void attn_kernel(
    const float* __restrict__ Y,
    const float* __restrict__ ATT,             // [4][512] (layer slice)
    const float* __restrict__ GBIAS,           // [2048]   (layer slice)
    const int* __restrict__ NPS,               // [32]
    const float* __restrict__ POOL,            // [192][2048] (layer 1 only)
    float* __restrict__ OUTF,                  // layer 1: graph_feat fp32
    unsigned short* __restrict__ OUTB) {       // layer 0: x1 bf16
    __shared__ float xls[6][512];
    __shared__ float xrs[6][512];
    __shared__ float atts[512];
    __shared__ float s_sm[6][6];
    __shared__ float alpha[6][6];

    int g = blockIdx.x, h = blockIdx.y;
    int tid = threadIdx.x;
    int cnt = NPS[g];

    for (int idx = tid; idx < 6 * 512; idx += 256) {
        int q = idx >> 9, d = idx & 511;
        size_t off = (size_t)(g * 6 + q) * 4096 + h * 512 + d;
        xls[q][d] = Y[off];
        xrs[q][d] = Y[off + 2048];
    }
    for (int d = tid; d < 512; d += 256) atts[d] = ATT[h * 512 + d];
    __syncthreads();

    // s[i][j] = sum_d att[d] * leaky_relu(xr[i][d] + xl[j][d], 0.2)
    int wv = tid >> 6, lane = tid & 63;
    for (int p = wv; p < 36; p += 4) {
        int i = p / 6, j = p % 6;
        float acc = 0.f;
        #pragma unroll
        for (int u = 0; u < 8; ++u) {
            int d = lane + u * 64;
            float v = xrs[i][d] + xls[j][d];
            v = (v >= 0.f) ? v : 0.2f * v;
            acc = fmaf(atts[d], v, acc);
        }
        #pragma unroll
        for (int off = 32; off; off >>= 1) acc += __shfl_down(acc, off);
        if (lane == 0) s_sm[i][j] = acc;
    }
    __syncthreads();

    // softmax per row over neighbor set (valid i -> all valid j; invalid -> self)
    if (tid < 6) {
        int i = tid;
        bool iv = i < cnt;
        float mx;
        if (iv) {
            mx = -1e30f;
            for (int j = 0; j < cnt; ++j) mx = fmaxf(mx, s_sm[i][j]);
        } else {
            mx = s_sm[i][i];
        }
        float e[6], sum = 0.f;
        for (int j = 0; j < 6; ++j) {
            bool nb = iv ? (j < cnt) : (j == i);
            e[j] = nb ? expf(s_sm[i][j] - mx) : 0.f;
            sum += e[j];
        }
        float inv = 1.f / sum;
        for (int j = 0; j < 6; ++j) alpha[i][j] = e[j] * inv;
    }
    __syncthreads();

    for (int idx = tid; idx < 6 * 512; idx += 256) {
        int q = idx >> 9, d = idx & 511;
        float acc = 0.f;
        #pragma unroll
        for (int j = 0; j < 6; ++j) acc = fmaf(alpha[q][j], xls[j][d], acc);
        int col = h * 512 + d;
        size_t off = (size_t)(g * 6 + q) * 2048 + col;
        float v = acc + GBIAS[col];
        if (LAYER == 0) {
            v = (v > 0.f) ? v : expm1f(v);      // ELU
            OUTB[off] = (unsigned short)f2bf(v);
        } else {
            OUTF[off] = v + POOL[off];          // graph_feat = x + pool
        }
    }
}

// ---- 4. Part-mean + BN
__global__ __launch_bounds__(256) void final_kernel(
    const float* __restrict__ GF, const float* __restrict__ GAMMA,
    const float* __restrict__ MEAN, const float* __restrict__ VAR,
    float* __restrict__ OUTP) {
    int idx = blockIdx.x * 256 + threadIdx.x;   // [0, 65536)
    int c = idx & 2047, b = idx >> 11;
    float acc = 0.f;
    #pragma unroll
    for (int p = 0; p < 6; ++p) acc += GF[(size_t)(p * 32 + b) * 2048 + c];
    acc *= (1.f / 6.f);
    OUTP[idx] = GAMMA[c] * (acc - MEAN[c]) * rsqrtf(VAR[c] + 1e-5f);
}

extern "C" void kernel_launch(void* const* d_in, const int* in_sizes, int n_in,
                              void* d_out, int out_size, void* d_ws, size_t ws_size,
                              hipStream_t stream) {
    const float* F     = (const float*)d_in[0];
    const int*   nps   = (const int*)d_in[1];
    const float* Wl    = (const float*)d_in[2];
    const float* bl    = (const float*)d_in[3];
    const float* Wr    = (const float*)d_in[4];
    const float* br    = (const float*)d_in[5];
    const float* att   = (const float*)d_in[6];
    const float* gb    = (const float*)d_in[7];
    const float* gamma = (const float*)d_in[8];
    const float* mean  = (const float*)d_in[9];
    const float* var   = (const float*)d_in[10];
    float* out = (float*)d_out;
    float* wsf = (float*)d_ws;

    const size_t SZ = (size_t)NNODES * CFEAT;   // 393216
    float* pool = wsf;                                        // [192][2048] f32
    float* gf   = wsf + SZ;                                   // [192][2048] f32
    float* Y    = wsf + 2 * SZ;                               // [192][4096] f32
    unsigned short* poolb = (unsigned short*)(wsf + 4 * SZ);  // bf16 [192][2048]
    unsigned short* x1b   = (unsigned short*)(wsf + 5 * SZ);  // bf16 [192][2048]

    const size_t WOFF = 4ull * 2048 * 512;       // per-layer weight stride

    // 1. pool (fp32 + bf16)
    pool_kernel<<<dim3(4096), dim3(256), 0, stream>>>(F, pool, poolb);

    // 2. layer 0
    gemm_kernel<<<dim3(128), dim3(256), 0, stream>>>(poolb, Wl, Wr, bl, br, Y);
    attn_kernel<0><<<dim3(32, 4), dim3(256), 0, stream>>>(Y, att, gb, nps,
                                                          nullptr, nullptr, x1b);

    // 3. layer 1
    gemm_kernel<<<dim3(128), dim3(256), 0, stream>>>(x1b, Wl + WOFF, Wr + WOFF,
                                                     bl + 2048, br + 2048, Y);
    attn_kernel<1><<<dim3(32, 4), dim3(256), 0, stream>>>(Y, att + 2048, gb + 2048,
                                                          nps, pool, gf, nullptr);

    // 4. part-mean + BN
    final_kernel<<<dim3(256), dim3(256), 0, stream>>>(gf, gamma, mean, var, out);
}